// Round 13
// baseline (115.276 us; speedup 1.0000x reference)
//
#include <hip/hip_runtime.h>
#include <hip/hip_bf16.h>

#define NHEAD 12
#define HD 64
#define SEQ 2048
#define NB 4
#define HDIM 768
#define MTOT (NB * SEQ)   // 8192

typedef float f32x4 __attribute__((ext_vector_type(4)));
typedef float f32x16 __attribute__((ext_vector_type(16)));
typedef short s16x8 __attribute__((ext_vector_type(8)));
typedef unsigned short u16x8 __attribute__((ext_vector_type(8)));

__device__ inline unsigned short f2bf(float f) {
    union { float f; unsigned u; } v; v.f = f;
    unsigned r = v.u + 0x7fffu + ((v.u >> 16) & 1u);
    return (unsigned short)(r >> 16);
}
__device__ inline float bf2f(unsigned short u) {
    union { unsigned u; float f; } v; v.u = ((unsigned)u) << 16;
    return v.f;
}
__device__ inline unsigned pack_bf2(float a, float b) {
    return (unsigned)f2bf(a) | ((unsigned)f2bf(b) << 16);
}
__device__ inline s16x8 mk_frag(uint2 lo, uint2 hi) {
    union { unsigned u[4]; s16x8 v; } r;
    r.u[0] = lo.x; r.u[1] = lo.y; r.u[2] = hi.x; r.u[3] = hi.y;
    return r.v;
}
__device__ inline void gload_lds16(const unsigned short* g, void* lds_base) {
    __builtin_amdgcn_global_load_lds(
        (const __attribute__((address_space(1))) void*)g,
        (__attribute__((address_space(3))) void*)lds_base, 16, 0, 0);
}

#define MFMA(acc, a, b) \
    acc = __builtin_amdgcn_mfma_f32_16x16x32_bf16((a), (b), (acc), 0, 0, 0)
#define MFMA32(acc, a, b) \
    acc = __builtin_amdgcn_mfma_f32_32x32x16_bf16((a), (b), (acc), 0, 0, 0)

// ---------------------------------------------------------------------------
// Merged prep: blocks [0,3072) convert X fp32->bf16; blocks [3072,3648)
// transpose+convert weights: Wq/Wk/Wv -> fused Wt[2304][768], Wo -> Wot.
// ---------------------------------------------------------------------------
__global__ __launch_bounds__(256) void prep_kernel(
    const float* __restrict__ X,
    const float* __restrict__ Wq, const float* __restrict__ Wk,
    const float* __restrict__ Wv, const float* __restrict__ Wo,
    unsigned short* __restrict__ Xb,
    unsigned short* __restrict__ Wt, unsigned short* __restrict__ Wot)
{
    __shared__ __align__(16) unsigned short ts[64][68];  // 136B stride
    const int t = threadIdx.x;
    const int bid = blockIdx.x;

    if (bid < 3072) {
        const int i = (bid * 256 + t) * 8;
        float4 a = *(const float4*)(X + i);
        float4 b = *(const float4*)(X + i + 4);
        ushort4 wa, wb;
        wa.x = f2bf(a.x); wa.y = f2bf(a.y); wa.z = f2bf(a.z); wa.w = f2bf(a.w);
        wb.x = f2bf(b.x); wb.y = f2bf(b.y); wb.z = f2bf(b.z); wb.w = f2bf(b.w);
        *(ushort4*)(Xb + i) = wa;
        *(ushort4*)(Xb + i + 4) = wb;
        return;
    }

    const int id = bid - 3072;          // 0..575
    const int z  = id / 144;            // weight index
    const int rem = id - z * 144;
    const int k0 = (rem / 12) * 64, n0 = (rem % 12) * 64;
    const float* W = (z == 0) ? Wq : (z == 1) ? Wk : (z == 2) ? Wv : Wo;
    unsigned short* D = (z < 3) ? (Wt + (size_t)z * HDIM * HDIM) : Wot;

    const int kr = (t >> 4) * 4;
    const int nc = (t & 15) * 4;
    #pragma unroll
    for (int r = 0; r < 4; r++) {
        float4 v = *(const float4*)(W + (size_t)(k0 + kr + r) * HDIM + n0 + nc);
        ushort4 w;
        w.x = f2bf(v.x); w.y = f2bf(v.y); w.z = f2bf(v.z); w.w = f2bf(v.w);
        *(ushort4*)&ts[kr + r][nc] = w;
    }
    __syncthreads();
    const int nr = t >> 2;
    const int kc = (t & 3) * 16;
    #pragma unroll
    for (int j4 = 0; j4 < 4; j4++) {
        ushort4 w;
        w.x = ts[kc + j4 * 4 + 0][nr];
        w.y = ts[kc + j4 * 4 + 1][nr];
        w.z = ts[kc + j4 * 4 + 2][nr];
        w.w = ts[kc + j4 * 4 + 3][nr];
        *(ushort4*)(D + (size_t)(n0 + nr) * HDIM + k0 + kc + j4 * 4) = w;
    }
}

// ---------------------------------------------------------------------------
// bf16 GEMM (R11-proven, reverted): 128x128 tile, BK=64, global_load_lds
// width=16 into linear LDS, XOR swizzle on global source + LDS read.
// 32x32x16 MFMA, 2x2 frags. Grid m-fast. Single-buffer: cross-block
// residency (4-5 blocks/CU) provides the latency hiding — R8/R12 proved
// trading it away loses.
// MODE 0: A=Xb, Bt=Wt[2304][768] -> Q/K head-major bf16 (Q scaled), V^T.
// MODE 1: A=Cb, Bt=Wot[768][768] -> out fp32 row-major + bias.
// ---------------------------------------------------------------------------
template<int MODE>
__global__ __launch_bounds__(256) void gemm_kernel(
    const unsigned short* __restrict__ A,
    const unsigned short* __restrict__ Bt,
    const float* __restrict__ bias0, const float* __restrict__ bias1,
    const float* __restrict__ bias2,
    unsigned short* __restrict__ Qb, unsigned short* __restrict__ Kb,
    unsigned short* __restrict__ Vb, float* __restrict__ out)
{
    __shared__ __align__(16) unsigned short As[128 * 64];
    __shared__ __align__(16) unsigned short Bs[128 * 64];

    const int t = threadIdx.x;
    const int lane = t & 63;
    const int wid = t >> 6;
    const int wm = wid >> 1, wn = wid & 1;
    const int l31 = lane & 31;
    const int lh = lane >> 5;

    const int m0 = blockIdx.x * 128;
    const int n0 = blockIdx.y * 128;

    int srow[4], scol[4];
    #pragma unroll
    for (int i = 0; i < 4; i++) {
        const int p = i * 4096 + t * 16;
        const int row = p >> 7;
        const int cb = p & 127;
        srow[i] = row;
        scol[i] = (cb ^ ((row & 7) << 4)) >> 1;
    }

    f32x16 acc[2][2] = {};

    for (int k0 = 0; k0 < HDIM; k0 += 64) {
        __syncthreads();
        #pragma unroll
        for (int i = 0; i < 4; i++)
            gload_lds16(A + (size_t)(m0 + srow[i]) * HDIM + k0 + scol[i],
                        (char*)As + i * 4096 + wid * 1024);
        #pragma unroll
        for (int i = 0; i < 4; i++)
            gload_lds16(Bt + (size_t)(n0 + srow[i]) * HDIM + k0 + scol[i],
                        (char*)Bs + i * 4096 + wid * 1024);
        __syncthreads();

        const int sw = (l31 & 7) << 4;
        #pragma unroll
        for (int kv = 0; kv < 4; kv++) {
            const int cb = (kv * 32 + lh * 16) ^ sw;
            s16x8 a0 = *(const s16x8*)((const char*)As + (wm * 64 +      l31) * 128 + cb);
            s16x8 a1 = *(const s16x8*)((const char*)As + (wm * 64 + 32 + l31) * 128 + cb);
            s16x8 b0 = *(const s16x8*)((const char*)Bs + (wn * 64 +      l31) * 128 + cb);
            s16x8 b1 = *(const s16x8*)((const char*)Bs + (wn * 64 + 32 + l31) * 128 + cb);
            MFMA32(acc[0][0], a0, b0);
            MFMA32(acc[0][1], a0, b1);
            MFMA32(acc[1][0], a1, b0);
            MFMA32(acc[1][1], a1, b1);
        }
    }

    if (MODE == 0) {
        const int z = n0 / HDIM;
        const float* bias = (z == 0) ? bias0 : (z == 1) ? bias1 : bias2;
        const float scale = (z == 0) ? 0.125f : 1.0f;
        unsigned short* dst = (z == 0) ? Qb : (z == 1) ? Kb : Vb;
        #pragma unroll
        for (int fm = 0; fm < 2; fm++) {
            #pragma unroll
            for (int fn = 0; fn < 2; fn++) {
                const int coll = (n0 - z * HDIM) + wn * 64 + fn * 32 + l31;
                const float bc = bias[coll];
                const int h = coll >> 6, d = coll & 63;
                #pragma unroll
                for (int reg = 0; reg < 16; reg++) {
                    const int rowD = (reg & 3) + 8 * (reg >> 2) + 4 * lh;
                    const int m = m0 + wm * 64 + fm * 32 + rowD;
                    const int b = m >> 11, s = m & (SEQ - 1);
                    const size_t idx = (z == 2)
                        ? ((((size_t)b * NHEAD + h) * HD + d) * SEQ + s)     // V^T
                        : ((((size_t)b * NHEAD + h) * SEQ + s) * HD + d);    // Q,K
                    dst[idx] = f2bf((acc[fm][fn][reg] + bc) * scale);
                }
            }
        }
    } else {
        #pragma unroll
        for (int fm = 0; fm < 2; fm++) {
            #pragma unroll
            for (int fn = 0; fn < 2; fn++) {
                const int col = n0 + wn * 64 + fn * 32 + l31;
                const float bc = bias0[col];
                #pragma unroll
                for (int reg = 0; reg < 16; reg++) {
                    const int rowD = (reg & 3) + 8 * (reg >> 2) + 4 * lh;
                    const int m = m0 + wm * 64 + fm * 32 + rowD;
                    out[(size_t)m * HDIM + col] = acc[fm][fn][reg] + bc;
                }
            }
        }
    }
}

// ---------------------------------------------------------------------------
// MFMA banded attention, QBLK=128 / 8 waves. Changes vs R11:
//  - K fragments loaded DIRECTLY from global (per-lane rows; L2-hot via the
//    XCD swizzle; address clamped to [0,SEQ) — band mask kills OOB values).
//    LDS staging now only V^T: 52 -> 27 KB, ~half the pre-barrier bytes.
// ---------------------------------------------------------------------------
__global__ __launch_bounds__(512) void attn_mfma(
    const unsigned short* __restrict__ Qb, const unsigned short* __restrict__ Kb,
    const unsigned short* __restrict__ Vtg, unsigned short* __restrict__ Cb)
{
    __shared__ __align__(16) unsigned short Vs[64][208];   // [d][key] (+zero pad)

    const int t = threadIdx.x;
    const int lane = t & 63;
    const int wq = t >> 6;                 // wave id 0..7
    const int woff = wq * 16;
    const int g = lane >> 4, r16 = lane & 15;

    // XCD swizzle: 768 blocks, 8 XCDs -> 96 per XCD = 6 heads x 16 q-tiles
    const int lid = blockIdx.y * 16 + blockIdx.x;
    const int wg = (lid & 7) * 96 + (lid >> 3);
    const int q0 = (wg & 15) * 128;
    const int bh = wg >> 4;

    const int b = bh / NHEAD, h = bh - b * NHEAD;
    const size_t base  = (size_t)bh * SEQ * HD;
    const size_t vbase = (size_t)bh * HD * SEQ;
    const int kstart = q0 - 32;
    const bool interior = (kstart >= 0) && (kstart + 191 < SEQ);

    // ---- stage V^T [64][192] + zero pad cols 192..207
    {
        const int row = t >> 3, c0 = (t & 7) * 24;
        const unsigned short* src = Vtg + vbase + (size_t)row * SEQ + kstart + c0;
        if (interior) {
            #pragma unroll
            for (int j = 0; j < 3; j++)
                *(u16x8*)&Vs[row][c0 + 8 * j] = *(const u16x8*)(src + 8 * j);
        } else {
            for (int e = 0; e < 24; e++) {
                const int s = kstart + c0 + e;
                Vs[row][c0 + e] = (s >= 0 && s < SEQ) ? src[e] : (unsigned short)0;
            }
        }
        if (t < 128) {
            const u16x8 z = {};
            *(u16x8*)&Vs[t >> 1][192 + (t & 1) * 8] = z;
        }
    }

    // ---- Q fragments direct from global (no LDS)
    s16x8 qf[2];
    {
        const unsigned short* gq = Qb + base + (size_t)(q0 + woff + r16) * HD;
        #pragma unroll
        for (int c = 0; c < 2; c++)
            qf[c] = mk_frag(*(const uint2*)(gq + c * 32 + 4 * g),
                            *(const uint2*)(gq + c * 32 + 16 + 4 * g));
    }

    // ---- QK^T (swapped), K fragments direct from global.
    // A-operand row per lane: s = kstart + woff + mf*16 + r16, clamped;
    // the band mask below nullifies any clamped/out-of-window value.
    f32x4 sacc[5] = {};
    #pragma unroll
    for (int mf = 0; mf < 5; mf++) {
        int s = kstart + woff + mf * 16 + r16;
        s = s < 0 ? 0 : (s > SEQ - 1 ? SEQ - 1 : s);
        const unsigned short* gk = Kb + base + (size_t)s * HD;
        #pragma unroll
        for (int c = 0; c < 2; c++) {
            s16x8 kf = mk_frag(*(const uint2*)(gk + c * 32 + 4 * g),
                               *(const uint2*)(gk + c * 32 + 16 + 4 * g));
            MFMA(sacc[mf], kf, qf[c]);
        }
    }

    // ---- band mask + in-register softmax (query = woff + r16)
    float mx = -1e30f;
    #pragma unroll
    for (int mf = 0; mf < 5; mf++) {
        #pragma unroll
        for (int r = 0; r < 4; r++) {
            const int rel = mf * 16 + 4 * g + r - r16;     // key - q_local in [0,64]
            const int sg = kstart + woff + mf * 16 + 4 * g + r;
            const bool ok = (rel >= 0) && (rel <= 64) && (sg >= 0) && (sg < SEQ);
            const float v = ok ? sacc[mf][r] : -1e30f;
            sacc[mf][r] = v;
            mx = fmaxf(mx, v);
        }
    }
    mx = fmaxf(mx, __shfl_xor(mx, 16));
    mx = fmaxf(mx, __shfl_xor(mx, 32));
    float l = 0.f;
    #pragma unroll
    for (int mf = 0; mf < 5; mf++) {
        #pragma unroll
        for (int r = 0; r < 4; r++) {
            const float e = __expf(sacc[mf][r] - mx);
            sacc[mf][r] = e;
            l += e;
        }
    }
    l += __shfl_xor(l, 16);
    l += __shfl_xor(l, 32);
    const float inv = 1.f / l;

    // ---- pack normalized P -> bf16 A-frags; chunk 2's upper half is zero
    s16x8 pf[3];
    #pragma unroll
    for (int c = 0; c < 3; c++) {
        union { unsigned u[4]; s16x8 v; } pv;
        pv.u[0] = pack_bf2(sacc[2 * c][0] * inv, sacc[2 * c][1] * inv);
        pv.u[1] = pack_bf2(sacc[2 * c][2] * inv, sacc[2 * c][3] * inv);
        if (c < 2) {
            pv.u[2] = pack_bf2(sacc[2 * c + 1][0] * inv, sacc[2 * c + 1][1] * inv);
            pv.u[3] = pack_bf2(sacc[2 * c + 1][2] * inv, sacc[2 * c + 1][3] * inv);
        } else {
            pv.u[2] = 0; pv.u[3] = 0;
        }
        pf[c] = pv.v;
    }

    __syncthreads();   // V^T tile ready

    // ---- PV over this wave's 96-key window (keys woff..woff+95)
    f32x4 cacc[4] = {};
    #pragma unroll
    for (int nf = 0; nf < 4; nf++) {
        const unsigned short* p = &Vs[nf * 16 + r16][woff];
        #pragma unroll
        for (int c = 0; c < 3; c++) {
            s16x8 vf = mk_frag(*(const uint2*)(p + c * 32 + 4 * g),
                               *(const uint2*)(p + c * 32 + 16 + 4 * g));
            MFMA(cacc[nf], pf[c], vf);
        }
    }

    // ---- write ctx bf16 [b][s][h][d]
    #pragma unroll
    for (int nf = 0; nf < 4; nf++) {
        #pragma unroll
        for (int r = 0; r < 4; r++) {
            const int ql = woff + 4 * g + r;
            const int d = nf * 16 + r16;
            Cb[(((size_t)b * SEQ + q0 + ql) * NHEAD + h) * HD + d] = f2bf(cacc[nf][r]);
        }
    }
}

// ---------------------------------------------------------------------------
extern "C" void kernel_launch(void* const* d_in, const int* in_sizes, int n_in,
                              void* d_out, int out_size, void* d_ws, size_t ws_size,
                              hipStream_t stream)
{
    const float* X  = (const float*)d_in[0];
    const float* Wq = (const float*)d_in[1];
    const float* bq = (const float*)d_in[2];
    const float* Wk = (const float*)d_in[3];
    const float* bk = (const float*)d_in[4];
    const float* Wv = (const float*)d_in[5];
    const float* bv = (const float*)d_in[6];
    const float* Wo = (const float*)d_in[7];
    const float* bo = (const float*)d_in[8];
    float* out = (float*)d_out;

    // Buffer plan:
    //   ws:    [0)        Xb bf16 12.58MB  (reused as Cb after qkv gemm)
    //          [12.58M)   Vt bf16 12.58MB  ([bh][d][s] transposed)
    //          [25.17M)   Wt bf16 [2304][768] 3.54MB
    //          [28.70M)   Wot bf16 [768][768] 1.18MB
    //   d_out: [0) Qb 12.58MB, [12.58M) Kb 12.58MB -> overwritten by final out
    char* ws = (char*)d_ws;
    unsigned short* Xb  = (unsigned short*)ws;
    unsigned short* Cb  = Xb;
    unsigned short* Vt  = (unsigned short*)(ws + 12582912);
    unsigned short* Wtp = (unsigned short*)(ws + 25165824);
    unsigned short* Wot = (unsigned short*)(ws + 28704768);
    unsigned short* Qb  = (unsigned short*)d_out;
    unsigned short* Kb  = (unsigned short*)((char*)d_out + 12582912);

    prep_kernel<<<dim3(3648), 256, 0, stream>>>(X, Wq, Wk, Wv, Wo, Xb, Wtp, Wot);
    gemm_kernel<0><<<dim3(64, 18), 256, 0, stream>>>(Xb, Wtp, bq, bk, bv, Qb, Kb, Vt, nullptr);
    attn_mfma<<<dim3(16, 48), 512, 0, stream>>>(Qb, Kb, Vt, Cb);
    gemm_kernel<1><<<dim3(64, 6), 256, 0, stream>>>(Cb, Wot, bo, nullptr, nullptr,
                                                    nullptr, nullptr, nullptr, out);
}

// Round 14
// 105.427 us; speedup vs baseline: 1.0934x; 1.0934x over previous
//
#include <hip/hip_runtime.h>
#include <hip/hip_bf16.h>

#define NHEAD 12
#define HD 64
#define SEQ 2048
#define NB 4
#define HDIM 768
#define MTOT (NB * SEQ)   // 8192

typedef float f32x4 __attribute__((ext_vector_type(4)));
typedef float f32x16 __attribute__((ext_vector_type(16)));
typedef short s16x8 __attribute__((ext_vector_type(8)));
typedef unsigned short u16x8 __attribute__((ext_vector_type(8)));

__device__ inline unsigned short f2bf(float f) {
    union { float f; unsigned u; } v; v.f = f;
    unsigned r = v.u + 0x7fffu + ((v.u >> 16) & 1u);
    return (unsigned short)(r >> 16);
}
__device__ inline float bf2f(unsigned short u) {
    union { unsigned u; float f; } v; v.u = ((unsigned)u) << 16;
    return v.f;
}
__device__ inline unsigned pack_bf2(float a, float b) {
    return (unsigned)f2bf(a) | ((unsigned)f2bf(b) << 16);
}
__device__ inline s16x8 mk_frag(uint2 lo, uint2 hi) {
    union { unsigned u[4]; s16x8 v; } r;
    r.u[0] = lo.x; r.u[1] = lo.y; r.u[2] = hi.x; r.u[3] = hi.y;
    return r.v;
}
__device__ inline void gload_lds16(const unsigned short* g, void* lds_base) {
    __builtin_amdgcn_global_load_lds(
        (const __attribute__((address_space(1))) void*)g,
        (__attribute__((address_space(3))) void*)lds_base, 16, 0, 0);
}

#define MFMA(acc, a, b) \
    acc = __builtin_amdgcn_mfma_f32_16x16x32_bf16((a), (b), (acc), 0, 0, 0)
#define MFMA32(acc, a, b) \
    acc = __builtin_amdgcn_mfma_f32_32x32x16_bf16((a), (b), (acc), 0, 0, 0)

// ---------------------------------------------------------------------------
// Merged prep: blocks [0,3072) convert X fp32->bf16; blocks [3072,3648)
// transpose+convert weights: Wq/Wk/Wv -> fused Wt[2304][768], Wo -> Wot.
// ---------------------------------------------------------------------------
__global__ __launch_bounds__(256) void prep_kernel(
    const float* __restrict__ X,
    const float* __restrict__ Wq, const float* __restrict__ Wk,
    const float* __restrict__ Wv, const float* __restrict__ Wo,
    unsigned short* __restrict__ Xb,
    unsigned short* __restrict__ Wt, unsigned short* __restrict__ Wot)
{
    __shared__ __align__(16) unsigned short ts[64][68];  // 136B stride
    const int t = threadIdx.x;
    const int bid = blockIdx.x;

    if (bid < 3072) {
        const int i = (bid * 256 + t) * 8;
        float4 a = *(const float4*)(X + i);
        float4 b = *(const float4*)(X + i + 4);
        ushort4 wa, wb;
        wa.x = f2bf(a.x); wa.y = f2bf(a.y); wa.z = f2bf(a.z); wa.w = f2bf(a.w);
        wb.x = f2bf(b.x); wb.y = f2bf(b.y); wb.z = f2bf(b.z); wb.w = f2bf(b.w);
        *(ushort4*)(Xb + i) = wa;
        *(ushort4*)(Xb + i + 4) = wb;
        return;
    }

    const int id = bid - 3072;          // 0..575
    const int z  = id / 144;            // weight index
    const int rem = id - z * 144;
    const int k0 = (rem / 12) * 64, n0 = (rem % 12) * 64;
    const float* W = (z == 0) ? Wq : (z == 1) ? Wk : (z == 2) ? Wv : Wo;
    unsigned short* D = (z < 3) ? (Wt + (size_t)z * HDIM * HDIM) : Wot;

    const int kr = (t >> 4) * 4;
    const int nc = (t & 15) * 4;
    #pragma unroll
    for (int r = 0; r < 4; r++) {
        float4 v = *(const float4*)(W + (size_t)(k0 + kr + r) * HDIM + n0 + nc);
        ushort4 w;
        w.x = f2bf(v.x); w.y = f2bf(v.y); w.z = f2bf(v.z); w.w = f2bf(v.w);
        *(ushort4*)&ts[kr + r][nc] = w;
    }
    __syncthreads();
    const int nr = t >> 2;
    const int kc = (t & 3) * 16;
    #pragma unroll
    for (int j4 = 0; j4 < 4; j4++) {
        ushort4 w;
        w.x = ts[kc + j4 * 4 + 0][nr];
        w.y = ts[kc + j4 * 4 + 1][nr];
        w.z = ts[kc + j4 * 4 + 2][nr];
        w.w = ts[kc + j4 * 4 + 3][nr];
        *(ushort4*)(D + (size_t)(n0 + nr) * HDIM + k0 + kc + j4 * 4) = w;
    }
}

// ---------------------------------------------------------------------------
// bf16 GEMM: BM x 128 tile, BK=64, global_load_lds width=16 into linear LDS,
// XOR swizzle on global source + LDS read. 32x32x16 MFMA. Grid m-fast.
// BM=128 (qkv): wave tile 64x64, 2x2 frags, 32KB LDS, grid 1152 (4.5/CU).
// BM=64  (out): wave tile 32x64, 1x2 frags, 24KB LDS, grid 768 (3/CU) —
//               fixes the 1.5-blocks/CU underfill of the 128-tile version.
// MODE 0: A=Xb, Bt=Wt[2304][768] -> Q/K head-major bf16 (Q scaled), V^T.
// MODE 1: A=Cb, Bt=Wot[768][768] -> out fp32 row-major + bias.
// ---------------------------------------------------------------------------
template<int MODE, int BM>
__global__ __launch_bounds__(256) void gemm_kernel(
    const unsigned short* __restrict__ A,
    const unsigned short* __restrict__ Bt,
    const float* __restrict__ bias0, const float* __restrict__ bias1,
    const float* __restrict__ bias2,
    unsigned short* __restrict__ Qb, unsigned short* __restrict__ Kb,
    unsigned short* __restrict__ Vb, float* __restrict__ out)
{
    constexpr int MF  = BM / 64;    // m-frags per wave (2 or 1)
    constexpr int CHA = BM / 32;    // A staging chunks per thread (4 or 2)

    __shared__ __align__(16) unsigned short As[BM * 64];
    __shared__ __align__(16) unsigned short Bs[128 * 64];

    const int t = threadIdx.x;
    const int lane = t & 63;
    const int wid = t >> 6;
    const int wm = wid >> 1, wn = wid & 1;
    const int l31 = lane & 31;
    const int lh = lane >> 5;

    const int m0 = blockIdx.x * BM;
    const int n0 = blockIdx.y * 128;

    // staging geometry: linear LDS dest; global source col XOR-swizzled by row
    int srow[4], scol[4];
    #pragma unroll
    for (int i = 0; i < 4; i++) {
        const int p = i * 4096 + t * 16;
        const int row = p >> 7;
        const int cb = p & 127;
        srow[i] = row;
        scol[i] = (cb ^ ((row & 7) << 4)) >> 1;
    }

    f32x16 acc[MF][2] = {};

    for (int k0 = 0; k0 < HDIM; k0 += 64) {
        __syncthreads();
        #pragma unroll
        for (int i = 0; i < CHA; i++)
            gload_lds16(A + (size_t)(m0 + srow[i]) * HDIM + k0 + scol[i],
                        (char*)As + i * 4096 + wid * 1024);
        #pragma unroll
        for (int i = 0; i < 4; i++)
            gload_lds16(Bt + (size_t)(n0 + srow[i]) * HDIM + k0 + scol[i],
                        (char*)Bs + i * 4096 + wid * 1024);
        __syncthreads();

        const int sw = (l31 & 7) << 4;
        #pragma unroll
        for (int kv = 0; kv < 4; kv++) {
            const int cb = (kv * 32 + lh * 16) ^ sw;
            s16x8 av[MF];
            #pragma unroll
            for (int j = 0; j < MF; j++)
                av[j] = *(const s16x8*)((const char*)As +
                        (wm * (BM / 2) + j * 32 + l31) * 128 + cb);
            s16x8 b0 = *(const s16x8*)((const char*)Bs + (wn * 64 +      l31) * 128 + cb);
            s16x8 b1 = *(const s16x8*)((const char*)Bs + (wn * 64 + 32 + l31) * 128 + cb);
            #pragma unroll
            for (int j = 0; j < MF; j++) {
                MFMA32(acc[j][0], av[j], b0);
                MFMA32(acc[j][1], av[j], b1);
            }
        }
    }

    // C/D map (verified): col = lane&31, row = (reg&3) + 8*(reg>>2) + 4*(lane>>5)
    if (MODE == 0) {
        const int z = n0 / HDIM;
        const float* bias = (z == 0) ? bias0 : (z == 1) ? bias1 : bias2;
        const float scale = (z == 0) ? 0.125f : 1.0f;
        unsigned short* dst = (z == 0) ? Qb : (z == 1) ? Kb : Vb;
        #pragma unroll
        for (int fm = 0; fm < MF; fm++) {
            #pragma unroll
            for (int fn = 0; fn < 2; fn++) {
                const int coll = (n0 - z * HDIM) + wn * 64 + fn * 32 + l31;
                const float bc = bias[coll];
                const int h = coll >> 6, d = coll & 63;
                #pragma unroll
                for (int reg = 0; reg < 16; reg++) {
                    const int rowD = (reg & 3) + 8 * (reg >> 2) + 4 * lh;
                    const int m = m0 + wm * (BM / 2) + fm * 32 + rowD;
                    const int b = m >> 11, s = m & (SEQ - 1);
                    const size_t idx = (z == 2)
                        ? ((((size_t)b * NHEAD + h) * HD + d) * SEQ + s)     // V^T
                        : ((((size_t)b * NHEAD + h) * SEQ + s) * HD + d);    // Q,K
                    dst[idx] = f2bf((acc[fm][fn][reg] + bc) * scale);
                }
            }
        }
    } else {
        #pragma unroll
        for (int fm = 0; fm < MF; fm++) {
            #pragma unroll
            for (int fn = 0; fn < 2; fn++) {
                const int col = n0 + wn * 64 + fn * 32 + l31;
                const float bc = bias0[col];
                #pragma unroll
                for (int reg = 0; reg < 16; reg++) {
                    const int rowD = (reg & 3) + 8 * (reg >> 2) + 4 * lh;
                    const int m = m0 + wm * (BM / 2) + fm * 32 + rowD;
                    out[(size_t)m * HDIM + col] = acc[fm][fn][reg] + bc;
                }
            }
        }
    }
}

// ---------------------------------------------------------------------------
// MFMA banded attention, QBLK=128 / 8 waves (R11-proven, restored verbatim).
// Q fragments direct from global; K staged over 512 threads; XCD swizzle.
// ---------------------------------------------------------------------------
__global__ __launch_bounds__(512) void attn_mfma(
    const unsigned short* __restrict__ Qb, const unsigned short* __restrict__ Kb,
    const unsigned short* __restrict__ Vtg, unsigned short* __restrict__ Cb)
{
    __shared__ __align__(16) unsigned short Ks[192][72];   // [key][d]
    __shared__ __align__(16) unsigned short Vs[64][208];   // [d][key] (+zero pad)

    const int t = threadIdx.x;
    const int lane = t & 63;
    const int wq = t >> 6;                 // wave id 0..7
    const int woff = wq * 16;
    const int g = lane >> 4, r16 = lane & 15;

    // XCD swizzle: 768 blocks, 8 XCDs -> 96 per XCD = 6 heads x 16 q-tiles
    const int lid = blockIdx.y * 16 + blockIdx.x;
    const int wg = (lid & 7) * 96 + (lid >> 3);
    const int q0 = (wg & 15) * 128;
    const int bh = wg >> 4;

    const int b = bh / NHEAD, h = bh - b * NHEAD;
    const size_t base  = (size_t)bh * SEQ * HD;
    const size_t vbase = (size_t)bh * HD * SEQ;
    const int kstart = q0 - 32;
    const bool interior = (kstart >= 0) && (kstart + 191 < SEQ);

    // ---- stage K [192][64]: 3 x 16B per thread
    #pragma unroll
    for (int i = 0; i < 3; i++) {
        const int u = i * 512 + t;         // 0..1535 16B units
        const int row = u >> 3, c16 = (u & 7) * 8;
        const int s = kstart + row;
        if (s >= 0 && s < SEQ) {
            *(u16x8*)&Ks[row][c16] =
                *(const u16x8*)(Kb + base + (size_t)s * HD + c16);
        } else {
            const u16x8 z = {};
            *(u16x8*)&Ks[row][c16] = z;
        }
    }
    // ---- stage V^T [64][192] + zero pad cols 192..207
    {
        const int row = t >> 3, c0 = (t & 7) * 24;
        const unsigned short* src = Vtg + vbase + (size_t)row * SEQ + kstart + c0;
        if (interior) {
            #pragma unroll
            for (int j = 0; j < 3; j++)
                *(u16x8*)&Vs[row][c0 + 8 * j] = *(const u16x8*)(src + 8 * j);
        } else {
            for (int e = 0; e < 24; e++) {
                const int s = kstart + c0 + e;
                Vs[row][c0 + e] = (s >= 0 && s < SEQ) ? src[e] : (unsigned short)0;
            }
        }
        if (t < 128) {
            const u16x8 z = {};
            *(u16x8*)&Vs[t >> 1][192 + (t & 1) * 8] = z;
        }
    }

    // ---- Q fragments direct from global (no LDS)
    s16x8 qf[2];
    {
        const unsigned short* gq = Qb + base + (size_t)(q0 + woff + r16) * HD;
        #pragma unroll
        for (int c = 0; c < 2; c++)
            qf[c] = mk_frag(*(const uint2*)(gq + c * 32 + 4 * g),
                            *(const uint2*)(gq + c * 32 + 16 + 4 * g));
    }
    __syncthreads();

    // ---- QK^T (swapped): 5 mf blocks cover this wave's band window
    f32x4 sacc[5] = {};
    #pragma unroll
    for (int mf = 0; mf < 5; mf++) {
        const unsigned short* p = &Ks[woff + mf * 16 + r16][0];
        #pragma unroll
        for (int c = 0; c < 2; c++) {
            s16x8 kf = mk_frag(*(const uint2*)(p + c * 32 + 4 * g),
                               *(const uint2*)(p + c * 32 + 16 + 4 * g));
            MFMA(sacc[mf], kf, qf[c]);
        }
    }

    // ---- band mask + in-register softmax (query = woff + r16)
    float mx = -1e30f;
    #pragma unroll
    for (int mf = 0; mf < 5; mf++) {
        #pragma unroll
        for (int r = 0; r < 4; r++) {
            const int rel = mf * 16 + 4 * g + r - r16;     // key - q_local in [0,64]
            const int sg = kstart + woff + mf * 16 + 4 * g + r;
            const bool ok = (rel >= 0) && (rel <= 64) && (sg >= 0) && (sg < SEQ);
            const float v = ok ? sacc[mf][r] : -1e30f;
            sacc[mf][r] = v;
            mx = fmaxf(mx, v);
        }
    }
    mx = fmaxf(mx, __shfl_xor(mx, 16));
    mx = fmaxf(mx, __shfl_xor(mx, 32));
    float l = 0.f;
    #pragma unroll
    for (int mf = 0; mf < 5; mf++) {
        #pragma unroll
        for (int r = 0; r < 4; r++) {
            const float e = __expf(sacc[mf][r] - mx);
            sacc[mf][r] = e;
            l += e;
        }
    }
    l += __shfl_xor(l, 16);
    l += __shfl_xor(l, 32);
    const float inv = 1.f / l;

    // ---- pack normalized P -> bf16 A-frags; chunk 2's upper half is zero
    s16x8 pf[3];
    #pragma unroll
    for (int c = 0; c < 3; c++) {
        union { unsigned u[4]; s16x8 v; } pv;
        pv.u[0] = pack_bf2(sacc[2 * c][0] * inv, sacc[2 * c][1] * inv);
        pv.u[1] = pack_bf2(sacc[2 * c][2] * inv, sacc[2 * c][3] * inv);
        if (c < 2) {
            pv.u[2] = pack_bf2(sacc[2 * c + 1][0] * inv, sacc[2 * c + 1][1] * inv);
            pv.u[3] = pack_bf2(sacc[2 * c + 1][2] * inv, sacc[2 * c + 1][3] * inv);
        } else {
            pv.u[2] = 0; pv.u[3] = 0;
        }
        pf[c] = pv.v;
    }

    // ---- PV over this wave's 96-key window (keys woff..woff+95)
    f32x4 cacc[4] = {};
    #pragma unroll
    for (int nf = 0; nf < 4; nf++) {
        const unsigned short* p = &Vs[nf * 16 + r16][woff];
        #pragma unroll
        for (int c = 0; c < 3; c++) {
            s16x8 vf = mk_frag(*(const uint2*)(p + c * 32 + 4 * g),
                               *(const uint2*)(p + c * 32 + 16 + 4 * g));
            MFMA(cacc[nf], pf[c], vf);
        }
    }

    // ---- write ctx bf16 [b][s][h][d]
    #pragma unroll
    for (int nf = 0; nf < 4; nf++) {
        #pragma unroll
        for (int r = 0; r < 4; r++) {
            const int ql = woff + 4 * g + r;
            const int d = nf * 16 + r16;
            Cb[(((size_t)b * SEQ + q0 + ql) * NHEAD + h) * HD + d] = f2bf(cacc[nf][r]);
        }
    }
}

// ---------------------------------------------------------------------------
extern "C" void kernel_launch(void* const* d_in, const int* in_sizes, int n_in,
                              void* d_out, int out_size, void* d_ws, size_t ws_size,
                              hipStream_t stream)
{
    const float* X  = (const float*)d_in[0];
    const float* Wq = (const float*)d_in[1];
    const float* bq = (const float*)d_in[2];
    const float* Wk = (const float*)d_in[3];
    const float* bk = (const float*)d_in[4];
    const float* Wv = (const float*)d_in[5];
    const float* bv = (const float*)d_in[6];
    const float* Wo = (const float*)d_in[7];
    const float* bo = (const float*)d_in[8];
    float* out = (float*)d_out;

    // Buffer plan:
    //   ws:    [0)        Xb bf16 12.58MB  (reused as Cb after qkv gemm)
    //          [12.58M)   Vt bf16 12.58MB  ([bh][d][s] transposed)
    //          [25.17M)   Wt bf16 [2304][768] 3.54MB
    //          [28.70M)   Wot bf16 [768][768] 1.18MB
    //   d_out: [0) Qb 12.58MB, [12.58M) Kb 12.58MB -> overwritten by final out
    char* ws = (char*)d_ws;
    unsigned short* Xb  = (unsigned short*)ws;
    unsigned short* Cb  = Xb;
    unsigned short* Vt  = (unsigned short*)(ws + 12582912);
    unsigned short* Wtp = (unsigned short*)(ws + 25165824);
    unsigned short* Wot = (unsigned short*)(ws + 28704768);
    unsigned short* Qb  = (unsigned short*)d_out;
    unsigned short* Kb  = (unsigned short*)((char*)d_out + 12582912);

    prep_kernel<<<dim3(3648), 256, 0, stream>>>(X, Wq, Wk, Wv, Wo, Xb, Wtp, Wot);
    gemm_kernel<0, 128><<<dim3(64, 18), 256, 0, stream>>>(Xb, Wtp, bq, bk, bv, Qb, Kb, Vt, nullptr);
    attn_mfma<<<dim3(16, 48), 512, 0, stream>>>(Qb, Kb, Vt, Cb);
    gemm_kernel<1, 64><<<dim3(128, 6), 256, 0, stream>>>(Cb, Wot, bo, nullptr, nullptr,
                                                         nullptr, nullptr, nullptr, out);
}